// Round 3
// baseline (42.974 us; speedup 1.0000x reference)
//
#include <hip/hip_runtime.h>

#define TLEN 4096
#define NTHREADS 512
#define PER (TLEN / NTHREADS)   // 8

typedef float f32x4 __attribute__((ext_vector_type(4)));

template<int DIL>
__device__ __forceinline__ void swt_taps(const float* __restrict__ src, int t,
                                         const float lo[8], const float hi[8],
                                         float& a, float& d)
{
    a = 0.f; d = 0.f;
    // taps span [t - 3*DIL, t + 4*DIL]
    if (t >= 3 * DIL && t < TLEN - 4 * DIL) {
        // interior: affine indices -> base + immediate-offset LDS reads, no mask VALU
#pragma unroll
        for (int j = 0; j < 8; ++j) {
            float v = src[t + (4 - j) * DIL];
            a = fmaf(lo[j], v, a);
            d = fmaf(hi[j], v, d);
        }
    } else {
#pragma unroll
        for (int j = 0; j < 8; ++j) {
            float v = src[(t + (4 - j) * DIL) & (TLEN - 1)];
            a = fmaf(lo[j], v, a);
            d = fmaf(hi[j], v, d);
        }
    }
}

__global__ __launch_bounds__(NTHREADS) void swt_db4_l3_kernel(
    const float* __restrict__ x,
    const float* __restrict__ lo_g,
    const float* __restrict__ hi_g,
    float* __restrict__ out)
{
    __shared__ float bufA[TLEN];
    __shared__ float bufB[TLEN];

    const int row = blockIdx.x;          // 0 .. B*N-1
    const int tid = threadIdx.x;

    // uniform-address filter loads -> scalar loads
    float lo[8], hi[8];
#pragma unroll
    for (int j = 0; j < 8; ++j) { lo[j] = lo_g[j]; hi[j] = hi_g[j]; }

    const float* xr = x + (size_t)row * TLEN;

    // Stage whole row into LDS: float4 global load + float4 LDS write.
#pragma unroll
    for (int k = 0; k < PER / 4; ++k) {
        int idx = (tid + k * NTHREADS) * 4;
        f32x4 v = *reinterpret_cast<const f32x4*>(xr + idx);
        *reinterpret_cast<f32x4*>(&bufA[idx]) = v;
    }
    __syncthreads();

    float D1[PER], D2[PER], D3[PER], A3[PER];

    // ---- Level 1: dil=1, bufA -> (D1 regs, A1 -> bufB) ----
#pragma unroll
    for (int k = 0; k < PER; ++k) {
        int t = tid + k * NTHREADS;
        float a, d;
        swt_taps<1>(bufA, t, lo, hi, a, d);
        D1[k] = d;
        bufB[t] = a;
    }
    __syncthreads();

    // ---- Level 2: dil=2, bufB -> (D2 regs, A2 -> bufA) ----
#pragma unroll
    for (int k = 0; k < PER; ++k) {
        int t = tid + k * NTHREADS;
        float a, d;
        swt_taps<2>(bufB, t, lo, hi, a, d);
        D2[k] = d;
        bufA[t] = a;   // level-2 reads all come from bufB; bufA re-read only after barrier
    }
    __syncthreads();

    // ---- Level 3: dil=4, bufA -> (D3, A3 regs) ----
#pragma unroll
    for (int k = 0; k < PER; ++k) {
        int t = tid + k * NTHREADS;
        float a, d;
        swt_taps<4>(bufA, t, lo, hi, a, d);
        D3[k] = d;
        A3[k] = a;
    }

    // ---- Store: out[row][t][0..3] = {A3, D3, D2, D1}; one nontemporal 16B store per t ----
    f32x4* outr = reinterpret_cast<f32x4*>(out + (size_t)row * TLEN * 4);
#pragma unroll
    for (int k = 0; k < PER; ++k) {
        int t = tid + k * NTHREADS;
        f32x4 v;
        v.x = A3[k]; v.y = D3[k]; v.z = D2[k]; v.w = D1[k];
        __builtin_nontemporal_store(v, &outr[t]);
    }
}

extern "C" void kernel_launch(void* const* d_in, const int* in_sizes, int n_in,
                              void* d_out, int out_size, void* d_ws, size_t ws_size,
                              hipStream_t stream) {
    const float* x  = (const float*)d_in[0];
    const float* lo = (const float*)d_in[1];
    const float* hi = (const float*)d_in[2];
    float* out = (float*)d_out;

    const int rows = 64 * 32;   // B * N
    swt_db4_l3_kernel<<<dim3(rows), dim3(NTHREADS), 0, stream>>>(x, lo, hi, out);
}

// Round 4
// 38.211 us; speedup vs baseline: 1.1247x; 1.1247x over previous
//
#include <hip/hip_runtime.h>

#define TLEN 4096
#define NTHREADS 512
#define PER (TLEN / NTHREADS)   // 8

typedef float f32x4 __attribute__((ext_vector_type(4)));

__global__ __launch_bounds__(NTHREADS) void swt_db4_l3_kernel(
    const float* __restrict__ x,
    const float* __restrict__ lo_g,
    const float* __restrict__ hi_g,
    float* __restrict__ out)
{
    __shared__ float bufA[TLEN];
    __shared__ float bufB[TLEN];

    const int row = blockIdx.x;          // 0 .. B*N-1
    const int tid = threadIdx.x;

    // uniform-address filter loads
    float lo[8], hi[8];
#pragma unroll
    for (int j = 0; j < 8; ++j) { lo[j] = lo_g[j]; hi[j] = hi_g[j]; }

    const float* xr = x + (size_t)row * TLEN;

    // Stage whole row into LDS: float4 global load + float4 LDS write.
#pragma unroll
    for (int k = 0; k < PER / 4; ++k) {
        int idx = (tid + k * NTHREADS) * 4;
        f32x4 v = *reinterpret_cast<const f32x4*>(xr + idx);
        *reinterpret_cast<f32x4*>(&bufA[idx]) = v;
    }
    __syncthreads();

    float D1[PER], D2[PER], D3[PER], A3[PER];

    // ---- Level 1: dil=1, bufA -> (D1 regs, A1 -> bufB) ----
#pragma unroll
    for (int k = 0; k < PER; ++k) {
        int t = tid + k * NTHREADS;
        float a = 0.f, d = 0.f;
#pragma unroll
        for (int j = 0; j < 8; ++j) {
            float v = bufA[(t + (4 - j)) & (TLEN - 1)];
            a = fmaf(lo[j], v, a);
            d = fmaf(hi[j], v, d);
        }
        D1[k] = d;
        bufB[t] = a;
    }
    __syncthreads();

    // ---- Level 2: dil=2, bufB -> (D2 regs, A2 -> bufA) ----
#pragma unroll
    for (int k = 0; k < PER; ++k) {
        int t = tid + k * NTHREADS;
        float a = 0.f, d = 0.f;
#pragma unroll
        for (int j = 0; j < 8; ++j) {
            float v = bufB[(t + (4 - j) * 2) & (TLEN - 1)];
            a = fmaf(lo[j], v, a);
            d = fmaf(hi[j], v, d);
        }
        D2[k] = d;
        bufA[t] = a;   // level-2 reads all come from bufB; bufA re-read only after barrier
    }
    __syncthreads();

    // ---- Level 3: dil=4, bufA -> (D3, A3 regs) ----
#pragma unroll
    for (int k = 0; k < PER; ++k) {
        int t = tid + k * NTHREADS;
        float a = 0.f, d = 0.f;
#pragma unroll
        for (int j = 0; j < 8; ++j) {
            float v = bufA[(t + (4 - j) * 4) & (TLEN - 1)];
            a = fmaf(lo[j], v, a);
            d = fmaf(hi[j], v, d);
        }
        D3[k] = d;
        A3[k] = a;
    }

    // ---- Store: out[row][t][0..3] = {A3, D3, D2, D1}; one plain 16B store per t ----
    f32x4* outr = reinterpret_cast<f32x4*>(out + (size_t)row * TLEN * 4);
#pragma unroll
    for (int k = 0; k < PER; ++k) {
        int t = tid + k * NTHREADS;
        f32x4 v;
        v.x = A3[k]; v.y = D3[k]; v.z = D2[k]; v.w = D1[k];
        outr[t] = v;
    }
}

extern "C" void kernel_launch(void* const* d_in, const int* in_sizes, int n_in,
                              void* d_out, int out_size, void* d_ws, size_t ws_size,
                              hipStream_t stream) {
    const float* x  = (const float*)d_in[0];
    const float* lo = (const float*)d_in[1];
    const float* hi = (const float*)d_in[2];
    float* out = (float*)d_out;

    const int rows = 64 * 32;   // B * N
    swt_db4_l3_kernel<<<dim3(rows), dim3(NTHREADS), 0, stream>>>(x, lo, hi, out);
}